// Round 15
// baseline (118.511 us; speedup 1.0000x reference)
//
#include <hip/hip_runtime.h>

// ---------------- problem constants ----------------
#define B_SAMPLES 8192
#define HID       512
#define NCLS      10
#define STYLE_D   64
#define LATENT_D  16

#define BM 128
#define BN 64
#define BK 64
#define MAXT    (B_SAMPLES/BM + NCLS)     // 74 worst-case expert row tiles
#define MAXROWS (B_SAMPLES + NCLS*BM)     // 9472 padded sorted rows

// prep_all flat-grid layout
#define PB_T512 (33 * 64)                 // 2112: 512x512 transposes
#define PB_UW3  (PB_T512 + 80)            // uw3: 10 cls x 8 k-tiles
#define PB_WT0  (PB_UW3 + 8)              // wt0: 8 n-tiles
#define PB_ZB   (PB_WT0 + 256)            // zb: 65536 chunk-items / 256
#define PB_TOT  (PB_ZB + 1)               // +1 grouping block

typedef short v8s __attribute__((ext_vector_type(8)));
typedef float v4f __attribute__((ext_vector_type(4)));

__device__ __forceinline__ short f2bf(float f) {
    union { float f; unsigned u; } x; x.f = f;
    unsigned r = x.u + 0x7fffu + ((x.u >> 16) & 1u);   // RNE; inputs finite
    return (short)(r >> 16);
}

__device__ __forceinline__ void gload16(const short* g, short* l) {
    __builtin_amdgcn_global_load_lds(
        (const __attribute__((address_space(1))) void*)g,
        (__attribute__((address_space(3))) void*)l, 16, 0, 0);
}

// global pre-swizzle: within each 64-elem slice of a row, XOR the 16B chunk
// index with (row&7). Writers store swizzled; global_load_lds copies rows
// linearly; fragment ds_reads XOR the same key (rule #21: both sides).
__device__ __forceinline__ int kswz(int row, int k) {
    return (k & ~63) + ((((k >> 3) & 7) ^ (row & 7)) << 3) + (k & 7);
}
__device__ __forceinline__ int cswz(int key, int n0, int c) {
    return n0 + ((((c >> 3) ^ key) & 7) << 3) + (c & 7);
}

// ---- vectorized 64x64 fp32->bf16 transpose tile (float4 in, short8 out) ----
// src: [k][n] fp32, row stride srcStride, rows >= kValid are zero.
// dst: [n][k] bf16, row stride dstStride, k-chunks pre-swizzled by row key.
__device__ __forceinline__ void t64(const float* __restrict__ s, int srcStride,
                                    int kValid, short* __restrict__ d,
                                    int dstStride, int k0, int n0, int t,
                                    float (*tile)[65]) {
    int tx = t & 15, ty = t >> 4;            // 16 x 16
    #pragma unroll
    for (int j = 0; j < 64; j += 16) {
        int k = k0 + ty + j;
        float4 v = make_float4(0.f, 0.f, 0.f, 0.f);
        if (k < kValid) v = *(const float4*)(s + (size_t)k * srcStride + n0 + tx * 4);
        *(float4*)&tile[ty + j][tx * 4] = v;
    }
    __syncthreads();
    #pragma unroll
    for (int wgt = 0; wgt < 2; ++wgt) {
        int wk = wgt * 256 + t;              // 0..511 work items
        int nl = wk >> 3, kc = wk & 7;
        int n = n0 + nl;
        v8s o;
        #pragma unroll
        for (int i = 0; i < 8; ++i) o[i] = f2bf(tile[kc * 8 + i][nl]);
        *(v8s*)(d + (size_t)n * dstStride + kswz(n, k0 + kc * 8)) = o;
    }
    __syncthreads();
}

// ---------------- one-dispatch prep: transposes + zb + grouping ----------------
__global__ __launch_bounds__(256) void prep_all(
    const float* __restrict__ z, const int* __restrict__ y,
    const float* __restrict__ sw0, const float* __restrict__ sw1,
    const float* __restrict__ sw2, const float* __restrict__ sw3,
    const float* __restrict__ uw0, const float* __restrict__ uw1,
    const float* __restrict__ uw2, const float* __restrict__ uw3,
    short* __restrict__ zb,
    short* __restrict__ wt0, short* __restrict__ wt1,
    short* __restrict__ wt2, short* __restrict__ wt3,
    short* __restrict__ wtu0, short* __restrict__ wtu1,
    short* __restrict__ wtu2, short* __restrict__ wtu3,
    int* __restrict__ tclass, int* __restrict__ trow0,
    int* __restrict__ order, int* __restrict__ rank) {

    __shared__ float tile[64][65];             // 16.6 KB
    const int b = blockIdx.x, t = threadIdx.x;

    if (b < PB_T512) {                         // 33 slices of 512x512
        int slice = b >> 6, tl = b & 63;
        int k0 = (tl >> 3) * 64, n0 = (tl & 7) * 64;
        const float* s; short* d;
        if      (slice == 0) { s = sw1; d = wt1; }
        else if (slice == 1) { s = sw2; d = wt2; }
        else if (slice == 2) { s = sw3; d = wt3; }
        else if (slice < 13) { size_t o = (size_t)(slice - 3)  * HID * HID; s = uw0 + o; d = wtu0 + o; }
        else if (slice < 23) { size_t o = (size_t)(slice - 13) * HID * HID; s = uw1 + o; d = wtu1 + o; }
        else                 { size_t o = (size_t)(slice - 23) * HID * HID; s = uw2 + o; d = wtu2 + o; }
        t64(s, HID, HID, d, HID, k0, n0, t, tile);
        return;
    }
    if (b < PB_UW3) {                          // uw3 [10][512][64] -> [10][64][512]
        int i = b - PB_T512;
        int cls = i >> 3, k0 = (i & 7) * 64;
        t64(uw3 + (size_t)cls * HID * STYLE_D, STYLE_D, HID,
            wtu3 + (size_t)cls * STYLE_D * HID, HID, k0, 0, t, tile);
        return;
    }
    if (b < PB_WT0) {                          // sw0 [16][512] -> wt0 [512][64]
        int n0 = (b - PB_UW3) * 64;
        t64(sw0, HID, LATENT_D, wt0, 64, 0, n0, t, tile);
        return;
    }
    if (b < PB_ZB) {                           // z [8192][16] -> zb [8192][64]
        int i = (b - PB_WT0) * 256 + t;        // chunk item: row=i>>3, chunk=i&7
        int row = i >> 3, c = i & 7;
        v8s o = {0, 0, 0, 0, 0, 0, 0, 0};
        if (c < 2) {
            float4 a = *(const float4*)(z + (size_t)row * LATENT_D + c * 8);
            float4 bb = *(const float4*)(z + (size_t)row * LATENT_D + c * 8 + 4);
            o[0] = f2bf(a.x); o[1] = f2bf(a.y); o[2] = f2bf(a.z); o[3] = f2bf(a.w);
            o[4] = f2bf(bb.x); o[5] = f2bf(bb.y); o[6] = f2bf(bb.z); o[7] = f2bf(bb.w);
        }
        *(v8s*)(zb + row * 64 + ((c ^ (row & 7)) << 3)) = o;
        return;
    }
    {                                          // grouping (one block)
        __shared__ int cnt[NCLS], cur[NCLS];
        if (t < NCLS) cnt[t] = 0;
        __syncthreads();
        for (int s2 = t; s2 < B_SAMPLES; s2 += 256) atomicAdd(&cnt[y[s2]], 1);
        __syncthreads();
        if (t == 0) {
            int off = 0, tt = 0;
            for (int c = 0; c < NCLS; ++c) {
                cur[c] = off;
                int nt = (cnt[c] + BM - 1) / BM;
                for (int j = 0; j < nt; ++j) { tclass[tt] = c; trow0[tt] = off + j * BM; ++tt; }
                off += nt * BM;
            }
            for (int u = tt; u < MAXT; ++u) { tclass[u] = -1; trow0[u] = 0; }
        }
        __syncthreads();
        for (int i = t; i < MAXROWS; i += 256) order[i] = -1;
        __syncthreads();
        for (int s2 = t; s2 < B_SAMPLES; s2 += 256) {
            int c = y[s2];
            int p = atomicAdd(&cur[c], 1);
            order[p] = s2;
            rank[s2] = p;
        }
    }
}

// ---------------- core GEMM: R9-proven 128x64, 2-phase, XCD-chunked ----------------
// MODE 0: trunk linear rows; 1: trunk L3 scatter-to-rank; 2: expert mid;
// 3: expert last (fp32 scatter to d_out).
template <int MODE>
__global__ __launch_bounds__(256, 2) void gemm2ph(
    const short* __restrict__ A, const short* __restrict__ WT,
    const float* __restrict__ bias, void* __restrict__ Outv,
    const int N, const int K, const long wStride, const int biasN,
    const int* __restrict__ aux, const int* __restrict__ tclass,
    const int* __restrict__ trow0) {

    // T1: bijective XCD-chunk remap (m204)
    const unsigned gx = gridDim.x;
    const unsigned nwg = gx * gridDim.y;
    unsigned lin = blockIdx.x + gx * blockIdx.y;
    {
        unsigned q = nwg >> 3, r = nwg & 7, xcd = lin & 7, idx = lin >> 3;
        lin = (xcd < r ? xcd * (q + 1) : r * (q + 1) + (xcd - r) * q) + idx;
    }
    const unsigned bx = lin % gx, by = lin / gx;

    int tile = by, cls = 0, row0;
    if (MODE <= 1) {
        row0 = tile * BM;
    } else {
        cls = tclass[tile];
        if (cls < 0) return;               // uniform block exit
        row0 = trow0[tile];
    }
    const int n0 = bx * BN;
    const short* wt = WT + (size_t)cls * wStride;
    const float* bs = bias + (size_t)cls * biasN;

    __shared__ short As[2][BM * BK];       // 2 x 16 KB
    __shared__ short Bs[2][BN * BK];       // 2 x  8 KB   -> 48 KB total

    const int t = threadIdx.x, lane = t & 63, w = t >> 6;
    const int srow = lane >> 3, scol = (lane & 7) * 8;   // 8 lanes x 16B per row
    const int wr = w >> 1, wc = w & 1;
    const int lrow = lane & 15, lko = lane >> 4;
    const int key = lrow & 7;

    v4f acc[4][2] = {};

    auto stage = [&](int buf, int k0) {
        #pragma unroll
        for (int p = 0; p < 4; ++p) {
            int row = p * 32 + w * 8 + srow;
            gload16(A + (size_t)(row0 + row) * K + k0 + scol, &As[buf][p * 2048 + w * 512]);
        }
        #pragma unroll
        for (int q2 = 0; q2 < 2; ++q2) {
            int row = q2 * 32 + w * 8 + srow;
            gload16(wt + (size_t)(n0 + row) * K + k0 + scol, &Bs[buf][q2 * 2048 + w * 512]);
        }
    };

    stage(0, 0);
    __syncthreads();
    const int nk = K / BK;
    for (int ks = 0; ks < nk; ++ks) {
        int buf = ks & 1;
        if (ks + 1 < nk) stage(buf ^ 1, (ks + 1) * BK);   // prefetch next tile

        #pragma unroll
        for (int kk = 0; kk < 2; ++kk) {
            int ch = ((kk * 4 + lko) ^ key) << 3;
            v8s af[4], bq[2];
            #pragma unroll
            for (int i = 0; i < 4; ++i)
                af[i] = *(const v8s*)&As[buf][(wr * 64 + i * 16 + lrow) * BK + ch];
            #pragma unroll
            for (int j = 0; j < 2; ++j)
                bq[j] = *(const v8s*)&Bs[buf][(wc * 32 + j * 16 + lrow) * BK + ch];
            #pragma unroll
            for (int i = 0; i < 4; ++i)
                #pragma unroll
                for (int j = 0; j < 2; ++j)
                    acc[i][j] = __builtin_amdgcn_mfma_f32_16x16x32_bf16(
                        af[i], bq[j], acc[i][j], 0, 0, 0);
        }
        __syncthreads();   // drains staged loads (aged under MFMA) + read fence
    }

    // ---- epilogue ----
    #pragma unroll
    for (int i = 0; i < 4; ++i)
        #pragma unroll
        for (int j = 0; j < 2; ++j)
            #pragma unroll
            for (int q3 = 0; q3 < 4; ++q3) {
                int rr = wr * 64 + i * 16 + lko * 4 + q3;  // C/D: row=(l>>4)*4+reg
                int c = wc * 32 + j * 16 + lrow;           //      col=l&15
                if (MODE == 3) {
                    int o = aux[row0 + rr];                // order (pos -> sample)
                    if (o >= 0)
                        ((float*)Outv)[(size_t)o * STYLE_D + n0 + c] = acc[i][j][q3] + bs[n0 + c];
                } else {
                    float v = fmaxf(acc[i][j][q3] + bs[n0 + c], 0.f);
                    int orow = (MODE == 1) ? aux[row0 + rr] : (row0 + rr);
                    ((short*)Outv)[(size_t)orow * N + cswz(orow & 7, n0, c)] = f2bf(v);
                }
            }
}

// ---------------- launcher ----------------
extern "C" void kernel_launch(void* const* d_in, const int* in_sizes, int n_in,
                              void* d_out, int out_size, void* d_ws, size_t ws_size,
                              hipStream_t stream) {
    const float* z   = (const float*)d_in[0];
    const int*   y   = (const int*)d_in[1];
    const float* sw0 = (const float*)d_in[2];
    const float* sb0 = (const float*)d_in[3];
    const float* sw1 = (const float*)d_in[4];
    const float* sb1 = (const float*)d_in[5];
    const float* sw2 = (const float*)d_in[6];
    const float* sb2 = (const float*)d_in[7];
    const float* sw3 = (const float*)d_in[8];
    const float* sb3 = (const float*)d_in[9];
    const float* uw0 = (const float*)d_in[10];
    const float* ub0 = (const float*)d_in[11];
    const float* uw1 = (const float*)d_in[12];
    const float* ub1 = (const float*)d_in[13];
    const float* uw2 = (const float*)d_in[14];
    const float* ub2 = (const float*)d_in[15];
    const float* uw3 = (const float*)d_in[16];
    const float* ub3 = (const float*)d_in[17];

    char* p = (char*)d_ws;
    auto alloc = [&](size_t bytes) -> char* {
        char* r = p; p += (bytes + 255) & ~(size_t)255; return r;
    };
    int*   tclass = (int*)alloc(MAXT * 4);
    int*   trow0  = (int*)alloc(MAXT * 4);
    int*   order  = (int*)alloc(MAXROWS * 4);
    int*   rank   = (int*)alloc(B_SAMPLES * 4);
    short* zb     = (short*)alloc((size_t)B_SAMPLES * 64 * 2);
    short* wt0    = (short*)alloc((size_t)HID * 64 * 2);
    short* wt1    = (short*)alloc((size_t)HID * HID * 2);
    short* wt2    = (short*)alloc((size_t)HID * HID * 2);
    short* wt3    = (short*)alloc((size_t)HID * HID * 2);
    short* wtu0   = (short*)alloc((size_t)NCLS * HID * HID * 2);
    short* wtu1   = (short*)alloc((size_t)NCLS * HID * HID * 2);
    short* wtu2   = (short*)alloc((size_t)NCLS * HID * HID * 2);
    short* wtu3   = (short*)alloc((size_t)NCLS * STYLE_D * HID * 2);
    short* act0   = (short*)alloc((size_t)MAXROWS * HID * 2);
    short* act1   = (short*)alloc((size_t)MAXROWS * HID * 2);
    short* act2   = (short*)alloc((size_t)MAXROWS * HID * 2);     // sorted trunk out

    prep_all<<<PB_TOT, 256, 0, stream>>>(
        z, y, sw0, sw1, sw2, sw3, uw0, uw1, uw2, uw3,
        zb, wt0, wt1, wt2, wt3, wtu0, wtu1, wtu2, wtu3,
        tclass, trow0, order, rank);

    // trunk
    gemm2ph<0><<<dim3(HID / BN, B_SAMPLES / BM), 256, 0, stream>>>(
        zb, wt0, sb0, act0, HID, 64, 0, 0, nullptr, nullptr, nullptr);
    gemm2ph<0><<<dim3(HID / BN, B_SAMPLES / BM), 256, 0, stream>>>(
        act0, wt1, sb1, act1, HID, HID, 0, 0, nullptr, nullptr, nullptr);
    gemm2ph<0><<<dim3(HID / BN, B_SAMPLES / BM), 256, 0, stream>>>(
        act1, wt2, sb2, act0, HID, HID, 0, 0, nullptr, nullptr, nullptr);
    gemm2ph<1><<<dim3(HID / BN, B_SAMPLES / BM), 256, 0, stream>>>(
        act0, wt3, sb3, act2, HID, HID, 0, 0, rank, nullptr, nullptr);

    // selected experts (class-grouped, sorted-linear rows)
    gemm2ph<2><<<dim3(HID / BN, MAXT), 256, 0, stream>>>(
        act2, wtu0, ub0, act0, HID, HID, (long)HID * HID, HID, nullptr, tclass, trow0);
    gemm2ph<2><<<dim3(HID / BN, MAXT), 256, 0, stream>>>(
        act0, wtu1, ub1, act1, HID, HID, (long)HID * HID, HID, nullptr, tclass, trow0);
    gemm2ph<2><<<dim3(HID / BN, MAXT), 256, 0, stream>>>(
        act1, wtu2, ub2, act0, HID, HID, (long)HID * HID, HID, nullptr, tclass, trow0);
    gemm2ph<3><<<dim3(1, MAXT), 256, 0, stream>>>(
        act0, wtu3, ub3, d_out, HID, HID, (long)STYLE_D * HID, STYLE_D, order, tclass, trow0);
}